// Round 2
// baseline (698.434 us; speedup 1.0000x reference)
//
#include <hip/hip_runtime.h>
#include <hip/hip_bf16.h>
#include <cstdint>
#include <cstddef>

#define B_ 16384
#define F_ 4096
#define P_ 32
#define D_ 128
#define TPB 4          // row-tiles (of 128 rows) per block
#define STRIPS 32      // strips per partition; grid = P_*STRIPS = 1024 blocks

using f32x4 = __attribute__((ext_vector_type(4))) float;
using s16x8 = __attribute__((ext_vector_type(8))) short;

union abuf { s16x8 v; uint32_t u[4]; };

__device__ inline uint32_t pk_bf16(float a, float b) {
    float2 f; f.x = a; f.y = b;
    union { __hip_bfloat162 h; uint32_t u; } cv;
    cv.h = __float22bfloat162_rn(f);
    return cv.u;
}

// tanh(z) = 1 - 2/(e^{2z}+1); callers pass z2 = 2*z (folded into BN scale)
__device__ inline float tanh_from_2z(float z2) {
    float e = __expf(z2);
    return 1.f - 2.f * __builtin_amdgcn_rcpf(e + 1.f);
}

// Stage W[p] (128x128 f32, row-major [k][c]) into LDS in MFMA B-fragment
// order: slot(j,s,l4,l15) at byte slot*16 holds bf16 W[s*32+l4*8+t][j*16+l15]
// for t=0..7, slot = ((j*4+s)*4 + l4)*16 + l15. A wave's read for (j,s) is
// then a contiguous 1KB block (lane*16) -> conflict-free ds_read_b128.
__device__ inline void stage_w(const float* __restrict__ Wp, short* s_w, int tid) {
#pragma unroll
    for (int it = 0; it < 8; ++it) {
        int slot = it * 256 + tid;
        int l15 = slot & 15;
        int l4  = (slot >> 4) & 3;
        int s   = (slot >> 6) & 3;
        int j   = slot >> 8;
        const float* src = Wp + (size_t)(s * 32 + l4 * 8) * D_ + j * 16 + l15;
        abuf a;
#pragma unroll
        for (int q = 0; q < 4; ++q) {
            float w0 = src[(size_t)(2 * q) * D_];
            float w1 = src[(size_t)(2 * q + 1) * D_];
            a.u[q] = pk_bf16(w0, w1);
        }
        *(s16x8*)((char*)s_w + (size_t)slot * 16) = a.v;
    }
}

// ------------- GEMM1: y1 = x @ BD(W1)  (bias1 cancels in BN), + stats ------
__global__ __launch_bounds__(256) void k_gemm1(
    const float* __restrict__ x, const float* __restrict__ W1,
    float* __restrict__ y1, float* __restrict__ gsum, float* __restrict__ gsq)
{
    __shared__ short s_w[D_ * D_];
    __shared__ float s_sum[D_], s_sq[D_];
    const int tid = threadIdx.x;
    const int p = blockIdx.x / STRIPS;
    const int strip = blockIdx.x % STRIPS;
    stage_w(W1 + (size_t)p * D_ * D_, s_w, tid);
    if (tid < D_) { s_sum[tid] = 0.f; s_sq[tid] = 0.f; }
    __syncthreads();

    const int wave = tid >> 6, lane = tid & 63;
    const int l15 = lane & 15, l4 = lane >> 4;
    const int lds_lane = lane * 16;

    float csum[8], csq[8];
#pragma unroll
    for (int j = 0; j < 8; ++j) { csum[j] = 0.f; csq[j] = 0.f; }

    for (int it = 0; it < TPB; ++it) {
        const int arow = (strip * TPB + it) * 128 + wave * 32;
        f32x4 acc[2][8];
#pragma unroll
        for (int i = 0; i < 2; ++i)
#pragma unroll
            for (int j = 0; j < 8; ++j) acc[i][j] = (f32x4){0.f, 0.f, 0.f, 0.f};

#pragma unroll
        for (int s = 0; s < 4; ++s) {
            abuf a[2];
#pragma unroll
            for (int i = 0; i < 2; ++i) {
                const float* ptr = x + (size_t)(arow + i * 16 + l15) * F_
                                     + p * D_ + s * 32 + l4 * 8;
                f32x4 v0 = *(const f32x4*)ptr;
                f32x4 v1 = *(const f32x4*)(ptr + 4);
                a[i].u[0] = pk_bf16(v0[0], v0[1]);
                a[i].u[1] = pk_bf16(v0[2], v0[3]);
                a[i].u[2] = pk_bf16(v1[0], v1[1]);
                a[i].u[3] = pk_bf16(v1[2], v1[3]);
            }
#pragma unroll
            for (int j = 0; j < 8; ++j) {
                s16x8 b = *(const s16x8*)((const char*)s_w
                              + (size_t)((j * 4 + s) * 1024) + lds_lane);
#pragma unroll
                for (int i = 0; i < 2; ++i)
                    acc[i][j] = __builtin_amdgcn_mfma_f32_16x16x32_bf16(a[i].v, b, acc[i][j], 0, 0, 0);
            }
        }
#pragma unroll
        for (int i = 0; i < 2; ++i) {
            const int rbase = arow + i * 16 + l4 * 4;
#pragma unroll
            for (int j = 0; j < 8; ++j) {
                float* yp = y1 + (size_t)rbase * F_ + p * D_ + j * 16 + l15;
#pragma unroll
                for (int r = 0; r < 4; ++r) {
                    float v = acc[i][j][r];
                    yp[(size_t)r * F_] = v;
                    csum[j] += v;
                    csq[j] = fmaf(v, v, csq[j]);
                }
            }
        }
    }
#pragma unroll
    for (int j = 0; j < 8; ++j) {
        float sm = csum[j], q = csq[j];
        sm += __shfl_xor(sm, 16); q += __shfl_xor(q, 16);
        sm += __shfl_xor(sm, 32); q += __shfl_xor(q, 32);
        if (l4 == 0) {
            atomicAdd(&s_sum[j * 16 + l15], sm);
            atomicAdd(&s_sq[j * 16 + l15], q);
        }
    }
    __syncthreads();
    if (tid < D_) {
        atomicAdd(&gsum[p * D_ + tid], s_sum[tid]);
        atomicAdd(&gsq[p * D_ + tid], s_sq[tid]);
    }
}

// -- GEMM2: y3 = tanh(bn1(y1)) @ BD(W2) + x (bias2 cancels in BN3), + stats -
__global__ __launch_bounds__(256) void k_gemm2(
    const float* __restrict__ x, float* __restrict__ yb /* y1 in, y3 out */,
    const float* __restrict__ W2,
    const float* __restrict__ sc2, const float* __restrict__ sh2,
    float* __restrict__ gsum, float* __restrict__ gsq)
{
    __shared__ short s_w[D_ * D_];
    __shared__ float s_sc[D_], s_sh[D_];
    __shared__ float s_sum[D_], s_sq[D_];
    const int tid = threadIdx.x;
    const int p = blockIdx.x / STRIPS;
    const int strip = blockIdx.x % STRIPS;
    stage_w(W2 + (size_t)p * D_ * D_, s_w, tid);
    if (tid < D_) {
        s_sc[tid] = sc2[p * D_ + tid];
        s_sh[tid] = sh2[p * D_ + tid];
        s_sum[tid] = 0.f; s_sq[tid] = 0.f;
    }
    __syncthreads();

    const int wave = tid >> 6, lane = tid & 63;
    const int l15 = lane & 15, l4 = lane >> 4;
    const int lds_lane = lane * 16;

    float csum[8], csq[8];
#pragma unroll
    for (int j = 0; j < 8; ++j) { csum[j] = 0.f; csq[j] = 0.f; }

    for (int it = 0; it < TPB; ++it) {
        const int arow = (strip * TPB + it) * 128 + wave * 32;
        f32x4 acc[2][8];
#pragma unroll
        for (int i = 0; i < 2; ++i)
#pragma unroll
            for (int j = 0; j < 8; ++j) acc[i][j] = (f32x4){0.f, 0.f, 0.f, 0.f};

#pragma unroll
        for (int s = 0; s < 4; ++s) {
            f32x4 scv0 = *(const f32x4*)&s_sc[s * 32 + l4 * 8];
            f32x4 scv1 = *(const f32x4*)&s_sc[s * 32 + l4 * 8 + 4];
            f32x4 shv0 = *(const f32x4*)&s_sh[s * 32 + l4 * 8];
            f32x4 shv1 = *(const f32x4*)&s_sh[s * 32 + l4 * 8 + 4];
            abuf a[2];
#pragma unroll
            for (int i = 0; i < 2; ++i) {
                const float* ptr = yb + (size_t)(arow + i * 16 + l15) * F_
                                      + p * D_ + s * 32 + l4 * 8;
                f32x4 v0 = *(const f32x4*)ptr;
                f32x4 v1 = *(const f32x4*)(ptr + 4);
                float t[8];
#pragma unroll
                for (int q = 0; q < 4; ++q) {
                    t[q]     = tanh_from_2z(fmaf(v0[q], scv0[q], shv0[q]));
                    t[q + 4] = tanh_from_2z(fmaf(v1[q], scv1[q], shv1[q]));
                }
                a[i].u[0] = pk_bf16(t[0], t[1]);
                a[i].u[1] = pk_bf16(t[2], t[3]);
                a[i].u[2] = pk_bf16(t[4], t[5]);
                a[i].u[3] = pk_bf16(t[6], t[7]);
            }
#pragma unroll
            for (int j = 0; j < 8; ++j) {
                s16x8 b = *(const s16x8*)((const char*)s_w
                              + (size_t)((j * 4 + s) * 1024) + lds_lane);
#pragma unroll
                for (int i = 0; i < 2; ++i)
                    acc[i][j] = __builtin_amdgcn_mfma_f32_16x16x32_bf16(a[i].v, b, acc[i][j], 0, 0, 0);
            }
        }
        // epilogue: + residual x, store y3 over y1 (each wave touches only
        // its own 32 rows; reads of this tile are already consumed)
#pragma unroll
        for (int i = 0; i < 2; ++i) {
            const int rbase = arow + i * 16 + l4 * 4;
#pragma unroll
            for (int j = 0; j < 8; ++j) {
                const size_t off = (size_t)rbase * F_ + p * D_ + j * 16 + l15;
                const float* xp = x + off;
                float* yp = yb + off;
#pragma unroll
                for (int r = 0; r < 4; ++r) {
                    float v = acc[i][j][r] + xp[(size_t)r * F_];
                    yp[(size_t)r * F_] = v;
                    csum[j] += v;
                    csq[j] = fmaf(v, v, csq[j]);
                }
            }
        }
    }
#pragma unroll
    for (int j = 0; j < 8; ++j) {
        float sm = csum[j], q = csq[j];
        sm += __shfl_xor(sm, 16); q += __shfl_xor(q, 16);
        sm += __shfl_xor(sm, 32); q += __shfl_xor(q, 32);
        if (l4 == 0) {
            atomicAdd(&s_sum[j * 16 + l15], sm);
            atomicAdd(&s_sq[j * 16 + l15], q);
        }
    }
    __syncthreads();
    if (tid < D_) {
        atomicAdd(&gsum[p * D_ + tid], s_sum[tid]);
        atomicAdd(&gsq[p * D_ + tid], s_sq[tid]);
    }
}

// --- BN finalize: outputs scale/shift pre-multiplied by 2 for tanh(2z/2) ---
__global__ void k_finalize(const float* __restrict__ sum,
                           const float* __restrict__ sumsq,
                           const float* __restrict__ gamma,
                           const float* __restrict__ beta,
                           float* __restrict__ sc2,
                           float* __restrict__ sh2)
{
    int f = blockIdx.x * blockDim.x + threadIdx.x;
    if (f < F_) {
        float mean = sum[f] * (1.f / B_);
        float var  = sumsq[f] * (1.f / B_) - mean * mean;
        float rstd = rsqrtf(var + 1e-5f);
        float sc = gamma[f] * rstd;
        sc2[f] = 2.f * sc;
        sh2[f] = 2.f * (beta[f] - mean * sc);
    }
}

// ----------- final elementwise: o3 = tanh(bn3(y3)), in place ---------------
__global__ void k_bn_tanh(float* yb, const float* __restrict__ sc2,
                          const float* __restrict__ sh2)
{
    const size_t n4 = (size_t)B_ * F_ / 4;
    size_t i = (size_t)blockIdx.x * blockDim.x + threadIdx.x;
    const size_t stride = (size_t)gridDim.x * blockDim.x;
    for (; i < n4; i += stride) {
        f32x4 v = ((const f32x4*)yb)[i];
        int col = (int)((i * 4) & (F_ - 1));
        f32x4 sc = *(const f32x4*)(sc2 + col);
        f32x4 sh = *(const f32x4*)(sh2 + col);
        f32x4 r;
#pragma unroll
        for (int t = 0; t < 4; ++t) r[t] = tanh_from_2z(fmaf(v[t], sc[t], sh[t]));
        ((f32x4*)yb)[i] = r;
    }
}

extern "C" void kernel_launch(void* const* d_in, const int* in_sizes, int n_in,
                              void* d_out, int out_size, void* d_ws, size_t ws_size,
                              hipStream_t stream) {
    const float* x      = (const float*)d_in[0];
    const float* W1     = (const float*)d_in[1];
    // d_in[2] = bias1 (cancels inside BN1 -> unused)
    const float* W2     = (const float*)d_in[3];
    // d_in[4] = bias2 (cancels inside BN3 -> unused)
    const float* gamma1 = (const float*)d_in[5];
    const float* beta1  = (const float*)d_in[6];
    const float* gamma3 = (const float*)d_in[7];
    const float* beta3  = (const float*)d_in[8];

    float* yb = (float*)d_out;          // y1 -> y3 -> o3, all in d_out
    float* S  = (float*)d_ws;
    float* sum1   = S;                  // zeroed
    float* sumsq1 = S + 4096;           // zeroed
    float* sum3   = S + 8192;           // zeroed
    float* sumsq3 = S + 12288;          // zeroed
    float* sc2_1  = S + 16384;
    float* sh2_1  = S + 20480;
    float* sc2_3  = S + 24576;
    float* sh2_3  = S + 28672;

    hipMemsetAsync(d_ws, 0, 4 * 4096 * sizeof(float), stream);

    k_gemm1<<<P_ * STRIPS, 256, 0, stream>>>(x, W1, yb, sum1, sumsq1);
    k_finalize<<<F_ / 256, 256, 0, stream>>>(sum1, sumsq1, gamma1, beta1, sc2_1, sh2_1);
    k_gemm2<<<P_ * STRIPS, 256, 0, stream>>>(x, yb, W2, sc2_1, sh2_1, sum3, sumsq3);
    k_finalize<<<F_ / 256, 256, 0, stream>>>(sum3, sumsq3, gamma3, beta3, sc2_3, sh2_3);
    k_bn_tanh<<<2048, 256, 0, stream>>>(yb, sc2_3, sh2_3);
}

// Round 3
// 655.576 us; speedup vs baseline: 1.0654x; 1.0654x over previous
//
#include <hip/hip_runtime.h>
#include <hip/hip_bf16.h>
#include <cstdint>
#include <cstddef>

#define B_ 16384
#define F_ 4096
#define P_ 32
#define D_ 128
#define STRIPS 32      // strips per partition; grid = P_*STRIPS = 1024 blocks
#define ITERS 8        // 8 iters x 64 rows (4 waves x 16 rows) = 512 rows/block

using f32x4 = __attribute__((ext_vector_type(4))) float;
using s16x8 = __attribute__((ext_vector_type(8))) short;

union abuf { s16x8 v; uint32_t u[4]; };

__device__ inline uint32_t pk_bf16(float a, float b) {
    float2 f; f.x = a; f.y = b;
    union { __hip_bfloat162 h; uint32_t u; } cv;
    cv.h = __float22bfloat162_rn(f);
    return cv.u;
}
__device__ inline unsigned short bf16_rn1(float f) {
    union { float f; uint32_t u; } v; v.f = f;
    return (unsigned short)((v.u + 0x7FFFu + ((v.u >> 16) & 1u)) >> 16);
}
__device__ inline float bf16_f32(unsigned short h) {
    union { uint32_t u; float f; } v; v.u = ((uint32_t)h) << 16;
    return v.f;
}
// tanh(z) = 1 - 2/(e^{2z}+1); caller passes ze = 2*log2(e)*z (folded into BN)
__device__ inline float tanh_e(float ze) {
    float e = __builtin_amdgcn_exp2f(ze);
    return 1.f - 2.f * __builtin_amdgcn_rcpf(e + 1.f);
}

// Stage W[p] (128x128 f32, row-major [k][c]) into LDS in MFMA B-fragment
// order: the 16B at slot = (j*4+s)*64 + lane holds bf16 W[s*32+(lane>>4)*8+t]
// [j*16+(lane&15)], t=0..7. A wave's read for (j,s) is a contiguous 1KB
// block (lane*16) -> conflict-free ds_read_b128 (verified: 0 conflicts).
__device__ inline void stage_w(const float* __restrict__ Wp, short* s_w, int tid) {
#pragma unroll
    for (int it = 0; it < 8; ++it) {
        int slot = it * 256 + tid;
        int l15 = slot & 15;
        int l4  = (slot >> 4) & 3;
        int s   = (slot >> 6) & 3;
        int j   = slot >> 8;
        const float* src = Wp + (size_t)(s * 32 + l4 * 8) * D_ + j * 16 + l15;
        abuf a;
#pragma unroll
        for (int q = 0; q < 4; ++q) {
            float w0 = src[(size_t)(2 * q) * D_];
            float w1 = src[(size_t)(2 * q + 1) * D_];
            a.u[q] = pk_bf16(w0, w1);
        }
        *(s16x8*)((char*)s_w + (size_t)slot * 16) = a.v;
    }
}

// ------------- GEMM1: y1 = x @ BD(W1)  (bias1 cancels in BN1), + stats -----
template<bool OB>
__global__ __launch_bounds__(256, 4) void k_gemm1(
    const float* __restrict__ x, const float* __restrict__ W1,
    float* __restrict__ y1f, unsigned short* __restrict__ y1h,
    float* __restrict__ gsum, float* __restrict__ gsq)
{
    __shared__ short s_w[D_ * D_];
    __shared__ float s_sum[D_], s_sq[D_];
    const int tid = threadIdx.x;
    const int p = blockIdx.x / STRIPS;
    const int strip = blockIdx.x % STRIPS;
    stage_w(W1 + (size_t)p * D_ * D_, s_w, tid);
    if (tid < D_) { s_sum[tid] = 0.f; s_sq[tid] = 0.f; }
    __syncthreads();

    const int wave = tid >> 6, lane = tid & 63;
    const int l15 = lane & 15, l4 = lane >> 4;
    const int ldsb = lane * 16;

    float csum[8], csq[8];
#pragma unroll
    for (int j = 0; j < 8; ++j) { csum[j] = 0.f; csq[j] = 0.f; }

    for (int it = 0; it < ITERS; ++it) {
        const int row0 = strip * (ITERS * 64) + it * 64 + wave * 16;
        const float* ap = x + (size_t)(row0 + l15) * F_ + p * D_ + l4 * 8;
        f32x4 v[4][2];
#pragma unroll
        for (int s = 0; s < 4; ++s) {
            v[s][0] = *(const f32x4*)(ap + s * 32);
            v[s][1] = *(const f32x4*)(ap + s * 32 + 4);
        }
        abuf a[4];
#pragma unroll
        for (int s = 0; s < 4; ++s) {
            a[s].u[0] = pk_bf16(v[s][0][0], v[s][0][1]);
            a[s].u[1] = pk_bf16(v[s][0][2], v[s][0][3]);
            a[s].u[2] = pk_bf16(v[s][1][0], v[s][1][1]);
            a[s].u[3] = pk_bf16(v[s][1][2], v[s][1][3]);
        }
        f32x4 acc[8];
#pragma unroll
        for (int j = 0; j < 8; ++j) acc[j] = (f32x4){0.f, 0.f, 0.f, 0.f};
#pragma unroll
        for (int s = 0; s < 4; ++s)
#pragma unroll
            for (int j = 0; j < 8; ++j) {
                s16x8 b = *(const s16x8*)((const char*)s_w + (j * 4 + s) * 1024 + ldsb);
                acc[j] = __builtin_amdgcn_mfma_f32_16x16x32_bf16(a[s].v, b, acc[j], 0, 0, 0);
            }
        const int rb = row0 + l4 * 4;
#pragma unroll
        for (int j = 0; j < 8; ++j) {
            const size_t off = (size_t)rb * F_ + p * D_ + j * 16 + l15;
#pragma unroll
            for (int r = 0; r < 4; ++r) {
                float vv = acc[j][r];
                if (OB) y1h[off + (size_t)r * F_] = bf16_rn1(vv);
                else    y1f[off + (size_t)r * F_] = vv;
                csum[j] += vv;
                csq[j] = fmaf(vv, vv, csq[j]);
            }
        }
    }
#pragma unroll
    for (int j = 0; j < 8; ++j) {
        float sm = csum[j], q = csq[j];
        sm += __shfl_xor(sm, 16); q += __shfl_xor(q, 16);
        sm += __shfl_xor(sm, 32); q += __shfl_xor(q, 32);
        if (l4 == 0) {
            atomicAdd(&s_sum[j * 16 + l15], sm);
            atomicAdd(&s_sq[j * 16 + l15], q);
        }
    }
    __syncthreads();
    if (tid < D_) {
        atomicAdd(&gsum[p * D_ + tid], s_sum[tid]);
        atomicAdd(&gsq[p * D_ + tid], s_sq[tid]);
    }
}

// -- GEMM2: y3 = tanh(bn1(y1)) @ BD(W2) + x (bias2 cancels in BN3), + stats -
template<bool IOB>
__global__ __launch_bounds__(256, 4) void k_gemm2(
    const float* __restrict__ x, float* __restrict__ yf,
    unsigned short* __restrict__ yh, const float* __restrict__ W2,
    const float* __restrict__ sce, const float* __restrict__ she,
    float* __restrict__ gsum, float* __restrict__ gsq)
{
    __shared__ short s_w[D_ * D_];
    __shared__ float s_sc[D_], s_sh[D_];
    __shared__ float s_sum[D_], s_sq[D_];
    const int tid = threadIdx.x;
    const int p = blockIdx.x / STRIPS;
    const int strip = blockIdx.x % STRIPS;
    stage_w(W2 + (size_t)p * D_ * D_, s_w, tid);
    if (tid < D_) {
        s_sc[tid] = sce[p * D_ + tid];
        s_sh[tid] = she[p * D_ + tid];
        s_sum[tid] = 0.f; s_sq[tid] = 0.f;
    }
    __syncthreads();

    const int wave = tid >> 6, lane = tid & 63;
    const int l15 = lane & 15, l4 = lane >> 4;
    const int ldsb = lane * 16;

    float csum[8], csq[8];
#pragma unroll
    for (int j = 0; j < 8; ++j) { csum[j] = 0.f; csq[j] = 0.f; }

    for (int it = 0; it < ITERS; ++it) {
        const int row0 = strip * (ITERS * 64) + it * 64 + wave * 16;
        s16x8 hv[4];
        f32x4 v[4][2];
        if (IOB) {
            const unsigned short* ap = yh + (size_t)(row0 + l15) * F_ + p * D_ + l4 * 8;
#pragma unroll
            for (int s = 0; s < 4; ++s) hv[s] = *(const s16x8*)(ap + s * 32);
        } else {
            const float* ap = yf + (size_t)(row0 + l15) * F_ + p * D_ + l4 * 8;
#pragma unroll
            for (int s = 0; s < 4; ++s) {
                v[s][0] = *(const f32x4*)(ap + s * 32);
                v[s][1] = *(const f32x4*)(ap + s * 32 + 4);
            }
        }
        abuf a[4];
#pragma unroll
        for (int s = 0; s < 4; ++s) {
            const int kb = s * 32 + l4 * 8;
            f32x4 sc0 = *(const f32x4*)&s_sc[kb];
            f32x4 sc1 = *(const f32x4*)&s_sc[kb + 4];
            f32x4 sh0 = *(const f32x4*)&s_sh[kb];
            f32x4 sh1 = *(const f32x4*)&s_sh[kb + 4];
            float t[8];
#pragma unroll
            for (int q = 0; q < 4; ++q) {
                float i0 = IOB ? bf16_f32((unsigned short)hv[s][q])     : v[s][0][q];
                float i1 = IOB ? bf16_f32((unsigned short)hv[s][q + 4]) : v[s][1][q];
                t[q]     = tanh_e(fmaf(i0, sc0[q], sh0[q]));
                t[q + 4] = tanh_e(fmaf(i1, sc1[q], sh1[q]));
            }
            a[s].u[0] = pk_bf16(t[0], t[1]);
            a[s].u[1] = pk_bf16(t[2], t[3]);
            a[s].u[2] = pk_bf16(t[4], t[5]);
            a[s].u[3] = pk_bf16(t[6], t[7]);
        }
        f32x4 acc[8];
#pragma unroll
        for (int j = 0; j < 8; ++j) acc[j] = (f32x4){0.f, 0.f, 0.f, 0.f};
#pragma unroll
        for (int s = 0; s < 4; ++s)
#pragma unroll
            for (int j = 0; j < 8; ++j) {
                s16x8 b = *(const s16x8*)((const char*)s_w + (j * 4 + s) * 1024 + ldsb);
                acc[j] = __builtin_amdgcn_mfma_f32_16x16x32_bf16(a[s].v, b, acc[j], 0, 0, 0);
            }
        // epilogue: + residual x, store y3 in place (wave's rows are private;
        // its y1 reads were consumed before these stores in program order)
        const int rb = row0 + l4 * 4;
#pragma unroll
        for (int j = 0; j < 8; ++j) {
            const size_t off = (size_t)rb * F_ + p * D_ + j * 16 + l15;
#pragma unroll
            for (int r = 0; r < 4; ++r) {
                float vv = acc[j][r] + x[off + (size_t)r * F_];
                if (IOB) yh[off + (size_t)r * F_] = bf16_rn1(vv);
                else     yf[off + (size_t)r * F_] = vv;
                csum[j] += vv;
                csq[j] = fmaf(vv, vv, csq[j]);
            }
        }
    }
#pragma unroll
    for (int j = 0; j < 8; ++j) {
        float sm = csum[j], q = csq[j];
        sm += __shfl_xor(sm, 16); q += __shfl_xor(q, 16);
        sm += __shfl_xor(sm, 32); q += __shfl_xor(q, 32);
        if (l4 == 0) {
            atomicAdd(&s_sum[j * 16 + l15], sm);
            atomicAdd(&s_sq[j * 16 + l15], q);
        }
    }
    __syncthreads();
    if (tid < D_) {
        atomicAdd(&gsum[p * D_ + tid], s_sum[tid]);
        atomicAdd(&gsq[p * D_ + tid], s_sq[tid]);
    }
}

// --- BN finalize: scale/shift pre-multiplied by 2*log2(e) for tanh_e -------
__global__ void k_finalize(const float* __restrict__ sum,
                           const float* __restrict__ sumsq,
                           const float* __restrict__ gamma,
                           const float* __restrict__ beta,
                           float* __restrict__ sce,
                           float* __restrict__ she)
{
    const float L2E2 = 2.f * 1.44269504088896340736f;
    int f = blockIdx.x * blockDim.x + threadIdx.x;
    if (f < F_) {
        float mean = sum[f] * (1.f / B_);
        float var  = sumsq[f] * (1.f / B_) - mean * mean;
        float rstd = rsqrtf(var + 1e-5f);
        float sc = gamma[f] * rstd;
        sce[f] = L2E2 * sc;
        she[f] = L2E2 * (beta[f] - mean * sc);
    }
}

// ----------- final elementwise: o3 = tanh(bn3(y3)) -> d_out (f32) ----------
template<bool IB>
__global__ void k_bn_tanh(const unsigned short* __restrict__ y3h,
                          float* __restrict__ outf,
                          const float* __restrict__ sce,
                          const float* __restrict__ she)
{
    if (IB) {
        const size_t n8 = (size_t)B_ * F_ / 8;
        size_t i = (size_t)blockIdx.x * blockDim.x + threadIdx.x;
        const size_t stride = (size_t)gridDim.x * blockDim.x;
        for (; i < n8; i += stride) {
            s16x8 hv = ((const s16x8*)y3h)[i];
            int col = (int)((i * 8) & (F_ - 1));
            f32x4 sc0 = *(const f32x4*)(sce + col);
            f32x4 sc1 = *(const f32x4*)(sce + col + 4);
            f32x4 sh0 = *(const f32x4*)(she + col);
            f32x4 sh1 = *(const f32x4*)(she + col + 4);
            f32x4 r0, r1;
#pragma unroll
            for (int t = 0; t < 4; ++t) {
                r0[t] = tanh_e(fmaf(bf16_f32((unsigned short)hv[t]),     sc0[t], sh0[t]));
                r1[t] = tanh_e(fmaf(bf16_f32((unsigned short)hv[t + 4]), sc1[t], sh1[t]));
            }
            ((f32x4*)outf)[i * 2]     = r0;
            ((f32x4*)outf)[i * 2 + 1] = r1;
        }
    } else {
        const size_t n4 = (size_t)B_ * F_ / 4;
        size_t i = (size_t)blockIdx.x * blockDim.x + threadIdx.x;
        const size_t stride = (size_t)gridDim.x * blockDim.x;
        for (; i < n4; i += stride) {
            f32x4 v = ((const f32x4*)outf)[i];
            int col = (int)((i * 4) & (F_ - 1));
            f32x4 sc = *(const f32x4*)(sce + col);
            f32x4 sh = *(const f32x4*)(she + col);
            f32x4 r;
#pragma unroll
            for (int t = 0; t < 4; ++t) r[t] = tanh_e(fmaf(v[t], sc[t], sh[t]));
            ((f32x4*)outf)[i] = r;
        }
    }
}

extern "C" void kernel_launch(void* const* d_in, const int* in_sizes, int n_in,
                              void* d_out, int out_size, void* d_ws, size_t ws_size,
                              hipStream_t stream) {
    const float* x      = (const float*)d_in[0];
    const float* W1     = (const float*)d_in[1];
    // d_in[2] = bias1 (cancels inside BN1)
    const float* W2     = (const float*)d_in[3];
    // d_in[4] = bias2 (cancels inside BN3)
    const float* gamma1 = (const float*)d_in[5];
    const float* beta1  = (const float*)d_in[6];
    const float* gamma3 = (const float*)d_in[7];
    const float* beta3  = (const float*)d_in[8];

    float* yf = (float*)d_out;                 // f32 fallback path buffer
    float* S  = (float*)d_ws;                  // 128KB stats block
    float* sum1   = S;                         // zeroed
    float* sumsq1 = S + 4096;                  // zeroed
    float* sum3   = S + 8192;                  // zeroed
    float* sumsq3 = S + 12288;                 // zeroed
    float* sce1   = S + 16384;
    float* she1   = S + 20480;
    float* sce3   = S + 24576;
    float* she3   = S + 28672;
    unsigned short* yh = (unsigned short*)((char*)d_ws + 128 * 1024);

    const bool big = ws_size >= (size_t)128 * 1024 + (size_t)B_ * F_ * 2;

    hipMemsetAsync(d_ws, 0, 4 * 4096 * sizeof(float), stream);

    if (big) {
        k_gemm1<true><<<P_ * STRIPS, 256, 0, stream>>>(x, W1, yf, yh, sum1, sumsq1);
        k_finalize<<<F_ / 256, 256, 0, stream>>>(sum1, sumsq1, gamma1, beta1, sce1, she1);
        k_gemm2<true><<<P_ * STRIPS, 256, 0, stream>>>(x, yf, yh, W2, sce1, she1, sum3, sumsq3);
        k_finalize<<<F_ / 256, 256, 0, stream>>>(sum3, sumsq3, gamma3, beta3, sce3, she3);
        k_bn_tanh<true><<<2048, 256, 0, stream>>>(yh, yf, sce3, she3);
    } else {
        k_gemm1<false><<<P_ * STRIPS, 256, 0, stream>>>(x, W1, yf, yh, sum1, sumsq1);
        k_finalize<<<F_ / 256, 256, 0, stream>>>(sum1, sumsq1, gamma1, beta1, sce1, she1);
        k_gemm2<false><<<P_ * STRIPS, 256, 0, stream>>>(x, yf, yh, W2, sce1, she1, sum3, sumsq3);
        k_finalize<<<F_ / 256, 256, 0, stream>>>(sum3, sumsq3, gamma3, beta3, sce3, she3);
        k_bn_tanh<false><<<2048, 256, 0, stream>>>(yh, yf, sce3, she3);
    }
}

// Round 4
// 530.890 us; speedup vs baseline: 1.3156x; 1.2349x over previous
//
#include <hip/hip_runtime.h>
#include <hip/hip_bf16.h>
#include <cstdint>
#include <cstddef>

#define B_ 16384
#define F_ 4096
#define P_ 32
#define D_ 128
#define STRIPS 32      // strips per partition; grid = P_*STRIPS = 1024 blocks
#define ITERS 8        // per wave: 8 tiles of 16 rows (4 waves -> 512 rows/block)

using f32x4 = __attribute__((ext_vector_type(4))) float;
using s16x8 = __attribute__((ext_vector_type(8))) short;

union abuf { s16x8 v; uint32_t u[4]; };

__device__ inline uint32_t pk_bf16(float a, float b) {
    float2 f; f.x = a; f.y = b;
    union { __hip_bfloat162 h; uint32_t u; } cv;
    cv.h = __float22bfloat162_rn(f);
    return cv.u;
}
__device__ inline float bf16_f32(unsigned short h) {
    union { uint32_t u; float f; } v; v.u = ((uint32_t)h) << 16;
    return v.f;
}
// tanh(z) = 1 - 2/(e^{2z}+1); caller passes ze = 2*log2(e)*z (folded into BN)
__device__ inline float tanh_e(float ze) {
    float e = __builtin_amdgcn_exp2f(ze);
    return 1.f - 2.f * __builtin_amdgcn_rcpf(e + 1.f);
}

// ---- W1 staging: A-operand fragments (swapped GEMM), k unpermuted ---------
// slot (j,s,l4,l15) at byte slot*16 holds bf16 W[s*32+l4*8+t][j*16+l15], t=0..7
// wave read for (j,s) = contiguous 1KB (lane*16) -> conflict-free ds_read_b128
__device__ inline void stage_w1(const float* __restrict__ Wp, short* s_w, int tid) {
#pragma unroll
    for (int it = 0; it < 8; ++it) {
        int slot = it * 256 + tid;
        int l15 = slot & 15;
        int l4  = (slot >> 4) & 3;
        int s   = (slot >> 6) & 3;
        int j   = slot >> 8;
        const float* src = Wp + (size_t)(s * 32 + l4 * 8) * D_ + j * 16 + l15;
        abuf a;
#pragma unroll
        for (int q = 0; q < 4; ++q)
            a.u[q] = pk_bf16(src[(size_t)(2 * q) * D_], src[(size_t)(2 * q + 1) * D_]);
        *(s16x8*)((char*)s_w + (size_t)slot * 16) = a.v;
    }
}

// ---- W2 staging: same, but k permuted to match the blocked y layout -------
// k(sp,l4,t) = sp*32 + (t>=4)*16 + l4*4 + (t&3)
__device__ inline void stage_w2(const float* __restrict__ Wp, short* s_w, int tid) {
#pragma unroll
    for (int it = 0; it < 8; ++it) {
        int slot = it * 256 + tid;
        int l15 = slot & 15;
        int l4  = (slot >> 4) & 3;
        int sp  = (slot >> 6) & 3;
        int j   = slot >> 8;
        const float* s0 = Wp + (size_t)(sp * 32 + l4 * 4) * D_ + j * 16 + l15;
        const float* s1 = s0 + (size_t)16 * D_;
        abuf a;
        a.u[0] = pk_bf16(s0[0],            s0[(size_t)D_]);
        a.u[1] = pk_bf16(s0[(size_t)2*D_], s0[(size_t)3*D_]);
        a.u[2] = pk_bf16(s1[0],            s1[(size_t)D_]);
        a.u[3] = pk_bf16(s1[(size_t)2*D_], s1[(size_t)3*D_]);
        *(s16x8*)((char*)s_w + (size_t)slot * 16) = a.v;
    }
}

// Blocked y layout (bf16): tile (g,p) = 16 rows x 128 cols = 4KB at element
// offset (g*32+p)*2048; within tile, unit (jp, lane) at jp*512 + lane*8 holds
// y[row g*16 + (lane&15)][cols jp*32 + (t>=4)*16 + (lane>>4)*4 + (t&3)].

// ------------- GEMM1: y1 = x @ BD(W1)  (bias1 cancels in BN1) --------------
template<bool BH>
__global__ __launch_bounds__(256, 4) void k_gemm1(
    const float* __restrict__ x, const float* __restrict__ W1,
    float* __restrict__ yf, unsigned short* __restrict__ yh)
{
    __shared__ short s_w[D_ * D_];
    const int tid = threadIdx.x;
    const int p = blockIdx.x / STRIPS, strip = blockIdx.x % STRIPS;
    stage_w1(W1 + (size_t)p * D_ * D_, s_w, tid);
    __syncthreads();
    const int wave = tid >> 6, lane = tid & 63;
    const int l15 = lane & 15, l4 = lane >> 4;
    const int ldsb = lane * 16;

    for (int it = 0; it < ITERS; ++it) {
        const int g = strip * 32 + it * 4 + wave;
        const int row = g * 16 + l15;
        const float* ap = x + (size_t)row * F_ + p * D_ + l4 * 8;
        f32x4 v0[4], v1[4];
#pragma unroll
        for (int s = 0; s < 4; ++s) {
            v0[s] = *(const f32x4*)(ap + s * 32);
            v1[s] = *(const f32x4*)(ap + s * 32 + 4);
        }
        abuf a[4];
#pragma unroll
        for (int s = 0; s < 4; ++s) {
            a[s].u[0] = pk_bf16(v0[s][0], v0[s][1]);
            a[s].u[1] = pk_bf16(v0[s][2], v0[s][3]);
            a[s].u[2] = pk_bf16(v1[s][0], v1[s][1]);
            a[s].u[3] = pk_bf16(v1[s][2], v1[s][3]);
        }
        f32x4 acc[8];
#pragma unroll
        for (int j = 0; j < 8; ++j) acc[j] = (f32x4){0.f, 0.f, 0.f, 0.f};
#pragma unroll
        for (int s = 0; s < 4; ++s)
#pragma unroll
            for (int j = 0; j < 8; ++j) {
                s16x8 w = *(const s16x8*)((const char*)s_w + (j * 4 + s) * 1024 + ldsb);
                acc[j] = __builtin_amdgcn_mfma_f32_16x16x32_bf16(w, a[s].v, acc[j], 0, 0, 0);
            }
        // acc[j][r] = y1[row][p*128 + j*16 + l4*4 + r]
        if (BH) {
            unsigned short* tp = yh + ((size_t)g * 32 + p) * 2048 + lane * 8;
#pragma unroll
            for (int jp = 0; jp < 4; ++jp) {
                abuf o;
                o.u[0] = pk_bf16(acc[2*jp][0],   acc[2*jp][1]);
                o.u[1] = pk_bf16(acc[2*jp][2],   acc[2*jp][3]);
                o.u[2] = pk_bf16(acc[2*jp+1][0], acc[2*jp+1][1]);
                o.u[3] = pk_bf16(acc[2*jp+1][2], acc[2*jp+1][3]);
                *(s16x8*)(tp + jp * 512) = o.v;
            }
        } else {
            float* rp = yf + (size_t)row * F_ + p * D_ + l4 * 4;
#pragma unroll
            for (int j = 0; j < 8; ++j) *(f32x4*)(rp + j * 16) = acc[j];
        }
    }
}

// -------- GEMM2: y3 = tanh(bn1(y1)) @ BD(W2) + x, in place -----------------
template<bool BH>
__global__ __launch_bounds__(256, 4) void k_gemm2(
    const float* __restrict__ x, float* __restrict__ yf,
    unsigned short* __restrict__ yh, const float* __restrict__ W2,
    const float* __restrict__ sce, const float* __restrict__ she)
{
    __shared__ short s_w[D_ * D_];
    __shared__ float s_sc[D_], s_sh[D_];
    const int tid = threadIdx.x;
    const int p = blockIdx.x / STRIPS, strip = blockIdx.x % STRIPS;
    stage_w2(W2 + (size_t)p * D_ * D_, s_w, tid);
    if (tid < D_) {
        s_sc[tid] = sce[p * D_ + tid];
        s_sh[tid] = she[p * D_ + tid];
    }
    __syncthreads();
    const int wave = tid >> 6, lane = tid & 63;
    const int l15 = lane & 15, l4 = lane >> 4;
    const int ldsb = lane * 16;

    for (int it = 0; it < ITERS; ++it) {
        const int g = strip * 32 + it * 4 + wave;
        const int row = g * 16 + l15;
        abuf a[4];
        if (BH) {
            const unsigned short* tp = yh + ((size_t)g * 32 + p) * 2048 + lane * 8;
            s16x8 hv[4];
#pragma unroll
            for (int sp = 0; sp < 4; ++sp) hv[sp] = *(const s16x8*)(tp + sp * 512);
#pragma unroll
            for (int sp = 0; sp < 4; ++sp) {
                const int kb = sp * 32 + l4 * 4;
                f32x4 sc0 = *(const f32x4*)&s_sc[kb], sc1 = *(const f32x4*)&s_sc[kb + 16];
                f32x4 sh0 = *(const f32x4*)&s_sh[kb], sh1 = *(const f32x4*)&s_sh[kb + 16];
                float t0[4], t1[4];
#pragma unroll
                for (int q = 0; q < 4; ++q) {
                    t0[q] = tanh_e(fmaf(bf16_f32((unsigned short)hv[sp][q]),     sc0[q], sh0[q]));
                    t1[q] = tanh_e(fmaf(bf16_f32((unsigned short)hv[sp][q + 4]), sc1[q], sh1[q]));
                }
                a[sp].u[0] = pk_bf16(t0[0], t0[1]);
                a[sp].u[1] = pk_bf16(t0[2], t0[3]);
                a[sp].u[2] = pk_bf16(t1[0], t1[1]);
                a[sp].u[3] = pk_bf16(t1[2], t1[3]);
            }
        } else {
            const float* ap = yf + (size_t)row * F_ + p * D_;
#pragma unroll
            for (int sp = 0; sp < 4; ++sp) {
                const int kb = sp * 32 + l4 * 4;
                f32x4 w0 = *(const f32x4*)(ap + kb);
                f32x4 w1 = *(const f32x4*)(ap + kb + 16);
                f32x4 sc0 = *(const f32x4*)&s_sc[kb], sc1 = *(const f32x4*)&s_sc[kb + 16];
                f32x4 sh0 = *(const f32x4*)&s_sh[kb], sh1 = *(const f32x4*)&s_sh[kb + 16];
                float t0[4], t1[4];
#pragma unroll
                for (int q = 0; q < 4; ++q) {
                    t0[q] = tanh_e(fmaf(w0[q], sc0[q], sh0[q]));
                    t1[q] = tanh_e(fmaf(w1[q], sc1[q], sh1[q]));
                }
                a[sp].u[0] = pk_bf16(t0[0], t0[1]);
                a[sp].u[1] = pk_bf16(t0[2], t0[3]);
                a[sp].u[2] = pk_bf16(t1[0], t1[1]);
                a[sp].u[3] = pk_bf16(t1[2], t1[3]);
            }
        }
        f32x4 acc[8];
#pragma unroll
        for (int j = 0; j < 8; ++j) acc[j] = (f32x4){0.f, 0.f, 0.f, 0.f};
#pragma unroll
        for (int sp = 0; sp < 4; ++sp)
#pragma unroll
            for (int j = 0; j < 8; ++j) {
                s16x8 w = *(const s16x8*)((const char*)s_w + (j * 4 + sp) * 1024 + ldsb);
                acc[j] = __builtin_amdgcn_mfma_f32_16x16x32_bf16(w, a[sp].v, acc[j], 0, 0, 0);
            }
        // + residual x; store y3 in place (wave-private tile, loads consumed)
        const float* xp = x + (size_t)row * F_ + p * D_ + l4 * 4;
#pragma unroll
        for (int j = 0; j < 8; ++j) {
            f32x4 xr = *(const f32x4*)(xp + j * 16);
#pragma unroll
            for (int r = 0; r < 4; ++r) acc[j][r] += xr[r];
        }
        if (BH) {
            unsigned short* tp = yh + ((size_t)g * 32 + p) * 2048 + lane * 8;
#pragma unroll
            for (int jp = 0; jp < 4; ++jp) {
                abuf o;
                o.u[0] = pk_bf16(acc[2*jp][0],   acc[2*jp][1]);
                o.u[1] = pk_bf16(acc[2*jp][2],   acc[2*jp][3]);
                o.u[2] = pk_bf16(acc[2*jp+1][0], acc[2*jp+1][1]);
                o.u[3] = pk_bf16(acc[2*jp+1][2], acc[2*jp+1][3]);
                *(s16x8*)(tp + jp * 512) = o.v;
            }
        } else {
            float* rp = yf + (size_t)row * F_ + p * D_ + l4 * 4;
#pragma unroll
            for (int j = 0; j < 8; ++j) *(f32x4*)(rp + j * 16) = acc[j];
        }
    }
}

// ------------- column stats: sum / sumsq over the batch dim ----------------
template<bool BH>
__global__ void k_stats(const float* __restrict__ yf,
                        const unsigned short* __restrict__ yh,
                        float* __restrict__ gsum, float* __restrict__ gsq)
{
    if (BH) {
        // grid 256: block = (p, 1/8th of g-range); thread = (jp,l4,l15)
        const int tid = threadIdx.x;
        const int p = blockIdx.x & 31, seg = blockIdx.x >> 5;
        const int jp = tid >> 6, l4 = (tid >> 4) & 3, l15 = tid & 15;
        const unsigned short* base = yh + (size_t)p * 2048 + jp * 512 + (l4 * 16 + l15) * 8;
        float cs[8], cq[8];
#pragma unroll
        for (int t = 0; t < 8; ++t) { cs[t] = 0.f; cq[t] = 0.f; }
        for (int g = seg * 128; g < seg * 128 + 128; ++g) {
            s16x8 hv = *(const s16x8*)(base + (size_t)g * 65536);
#pragma unroll
            for (int t = 0; t < 8; ++t) {
                float f = bf16_f32((unsigned short)hv[t]);
                cs[t] += f; cq[t] = fmaf(f, f, cq[t]);
            }
        }
#pragma unroll
        for (int t = 0; t < 8; ++t) {
            cs[t] += __shfl_xor(cs[t], 1); cq[t] += __shfl_xor(cq[t], 1);
            cs[t] += __shfl_xor(cs[t], 2); cq[t] += __shfl_xor(cq[t], 2);
            cs[t] += __shfl_xor(cs[t], 4); cq[t] += __shfl_xor(cq[t], 4);
            cs[t] += __shfl_xor(cs[t], 8); cq[t] += __shfl_xor(cq[t], 8);
        }
        if (l15 == 0) {
#pragma unroll
            for (int t = 0; t < 8; ++t) {
                int c = p * 128 + jp * 32 + (t >= 4 ? 16 : 0) + l4 * 4 + (t & 3);
                atomicAdd(&gsum[c], cs[t]);
                atomicAdd(&gsq[c],  cq[t]);
            }
        }
    } else {
        // grid 1024: thread -> (col-group, row phase), strided rows
        const int id = blockIdx.x * 256 + threadIdx.x;
        const int c4 = id & 1023;
        const int r0 = id >> 10;                 // 0..255
        const float* bp = yf + (size_t)r0 * F_ + c4 * 4;
        f32x4 cs = {0.f,0.f,0.f,0.f}, cq = {0.f,0.f,0.f,0.f};
        for (int k = 0; k < 64; ++k) {
            f32x4 v = *(const f32x4*)(bp + (size_t)k * 256 * F_);
#pragma unroll
            for (int t = 0; t < 4; ++t) { cs[t] += v[t]; cq[t] = fmaf(v[t], v[t], cq[t]); }
        }
#pragma unroll
        for (int t = 0; t < 4; ++t) {
            atomicAdd(&gsum[c4 * 4 + t], cs[t]);
            atomicAdd(&gsq[c4 * 4 + t],  cq[t]);
        }
    }
}

// --- BN finalize: scale/shift pre-multiplied by 2*log2(e) for tanh_e -------
__global__ void k_finalize(const float* __restrict__ sum,
                           const float* __restrict__ sumsq,
                           const float* __restrict__ gamma,
                           const float* __restrict__ beta,
                           float* __restrict__ sce, float* __restrict__ she)
{
    const float L2E2 = 2.f * 1.44269504088896340736f;
    int f = blockIdx.x * blockDim.x + threadIdx.x;
    if (f < F_) {
        float mean = sum[f] * (1.f / B_);
        float var  = sumsq[f] * (1.f / B_) - mean * mean;
        float rstd = rsqrtf(var + 1e-5f);
        float sc = gamma[f] * rstd;
        sce[f] = L2E2 * sc;
        she[f] = L2E2 * (beta[f] - mean * sc);
    }
}

// ----------- final elementwise: o3 = tanh(bn3(y3)) -> d_out (f32) ----------
template<bool BH>
__global__ void k_bn_tanh(const unsigned short* __restrict__ yh,
                          float* __restrict__ out,
                          const float* __restrict__ sce,
                          const float* __restrict__ she)
{
    if (BH) {
        const size_t NU = (size_t)B_ / 16 * P_ * 256;   // 8M 16-byte units
        size_t idx = (size_t)blockIdx.x * blockDim.x + threadIdx.x;
        const size_t stride = (size_t)gridDim.x * blockDim.x;
        for (; idx < NU; idx += stride) {
            s16x8 hv = *(const s16x8*)(yh + idx * 8);
            int g = (int)(idx >> 13);
            int rem = (int)(idx & 8191);
            int p = rem >> 8, s = rem & 255;
            int jp = s >> 6, l4 = (s >> 4) & 3, l15 = s & 15;
            int c0 = p * 128 + jp * 32 + l4 * 4;
            int row = g * 16 + l15;
            f32x4 sc0 = *(const f32x4*)(sce + c0), sc1 = *(const f32x4*)(sce + c0 + 16);
            f32x4 sh0 = *(const f32x4*)(she + c0), sh1 = *(const f32x4*)(she + c0 + 16);
            f32x4 r0, r1;
#pragma unroll
            for (int t = 0; t < 4; ++t) {
                r0[t] = tanh_e(fmaf(bf16_f32((unsigned short)hv[t]),     sc0[t], sh0[t]));
                r1[t] = tanh_e(fmaf(bf16_f32((unsigned short)hv[t + 4]), sc1[t], sh1[t]));
            }
            float* op = out + (size_t)row * F_ + c0;
            *(f32x4*)op = r0;
            *(f32x4*)(op + 16) = r1;
        }
    } else {
        const size_t n4 = (size_t)B_ * F_ / 4;
        size_t i = (size_t)blockIdx.x * blockDim.x + threadIdx.x;
        const size_t stride = (size_t)gridDim.x * blockDim.x;
        for (; i < n4; i += stride) {
            f32x4 v = ((const f32x4*)out)[i];
            int col = (int)((i * 4) & (F_ - 1));
            f32x4 sc = *(const f32x4*)(sce + col);
            f32x4 sh = *(const f32x4*)(she + col);
            f32x4 r;
#pragma unroll
            for (int t = 0; t < 4; ++t) r[t] = tanh_e(fmaf(v[t], sc[t], sh[t]));
            ((f32x4*)out)[i] = r;
        }
    }
}

extern "C" void kernel_launch(void* const* d_in, const int* in_sizes, int n_in,
                              void* d_out, int out_size, void* d_ws, size_t ws_size,
                              hipStream_t stream) {
    const float* x      = (const float*)d_in[0];
    const float* W1     = (const float*)d_in[1];
    // d_in[2] = bias1 (cancels inside BN1)
    const float* W2     = (const float*)d_in[3];
    // d_in[4] = bias2 (cancels inside BN3)
    const float* gamma1 = (const float*)d_in[5];
    const float* beta1  = (const float*)d_in[6];
    const float* gamma3 = (const float*)d_in[7];
    const float* beta3  = (const float*)d_in[8];

    float* yf = (float*)d_out;
    float* S  = (float*)d_ws;                  // 128KB stats block
    float* sum1   = S;                         // zeroed
    float* sq1    = S + 4096;                  // zeroed
    float* sum3   = S + 8192;                  // zeroed
    float* sq3    = S + 12288;                 // zeroed
    float* sce1   = S + 16384;
    float* she1   = S + 20480;
    float* sce3   = S + 24576;
    float* she3   = S + 28672;
    unsigned short* yh = (unsigned short*)((char*)d_ws + 128 * 1024);

    const bool big = ws_size >= (size_t)128 * 1024 + (size_t)B_ * F_ * 2;

    hipMemsetAsync(d_ws, 0, 4 * 4096 * sizeof(float), stream);

    if (big) {
        k_gemm1<true><<<P_ * STRIPS, 256, 0, stream>>>(x, W1, yf, yh);
        k_stats<true><<<256, 256, 0, stream>>>(yf, yh, sum1, sq1);
        k_finalize<<<F_ / 256, 256, 0, stream>>>(sum1, sq1, gamma1, beta1, sce1, she1);
        k_gemm2<true><<<P_ * STRIPS, 256, 0, stream>>>(x, yf, yh, W2, sce1, she1);
        k_stats<true><<<256, 256, 0, stream>>>(yf, yh, sum3, sq3);
        k_finalize<<<F_ / 256, 256, 0, stream>>>(sum3, sq3, gamma3, beta3, sce3, she3);
        k_bn_tanh<true><<<8192, 256, 0, stream>>>(yh, yf, sce3, she3);
    } else {
        k_gemm1<false><<<P_ * STRIPS, 256, 0, stream>>>(x, W1, yf, yh);
        k_stats<false><<<1024, 256, 0, stream>>>(yf, yh, sum1, sq1);
        k_finalize<<<F_ / 256, 256, 0, stream>>>(sum1, sq1, gamma1, beta1, sce1, she1);
        k_gemm2<false><<<P_ * STRIPS, 256, 0, stream>>>(x, yf, yh, W2, sce1, she1);
        k_stats<false><<<1024, 256, 0, stream>>>(yf, yh, sum3, sq3);
        k_finalize<<<F_ / 256, 256, 0, stream>>>(sum3, sq3, gamma3, beta3, sce3, she3);
        k_bn_tanh<false><<<4096, 256, 0, stream>>>(yh, yf, sce3, she3);
    }
}